// Round 1
// baseline (479.009 us; speedup 1.0000x reference)
//
#include <hip/hip_runtime.h>
#include <math.h>

#define B_   8
#define C_   64
#define CK_  8
#define L_   4096
#define LT_  64   // l tile
#define MT_  64   // m tile (columns per workgroup)

// ---------------- Kernel 1: QKV projection (1x1 conv) ----------------
// x: [B, C, L]  ->  q: [B, L, CK] ; k: [B, CK, L] ; vT: [B, L, C]
__global__ __launch_bounds__(256) void qkv_kernel(
    const float* __restrict__ x,
    const float* __restrict__ Wq, const float* __restrict__ bq,
    const float* __restrict__ Wk, const float* __restrict__ bk,
    const float* __restrict__ Wv, const float* __restrict__ bv,
    float* __restrict__ qo, float* __restrict__ ko, float* __restrict__ vTo)
{
    __shared__ float LWq[CK_ * C_];   // [o][c]
    __shared__ float LWk[CK_ * C_];   // [o][c]
    __shared__ float LWvT[C_ * C_];   // [c_in][c_out]  (transposed for float4 reads)
    const int tid = threadIdx.x;

    ((float2*)LWq)[tid] = ((const float2*)Wq)[tid];   // 512 floats
    ((float2*)LWk)[tid] = ((const float2*)Wk)[tid];
    #pragma unroll
    for (int j = 0; j < 16; ++j) {
        int f = tid + j * 256;                         // f = c_out*64 + c_in
        LWvT[(f & 63) * C_ + (f >> 6)] = Wv[f];
    }
    __syncthreads();

    const int b = blockIdx.x >> 4;                     // 16 blocks per batch
    const int l = ((blockIdx.x & 15) << 8) + tid;

    float qa[CK_], ka[CK_], va[C_];
    #pragma unroll
    for (int o = 0; o < CK_; ++o) { qa[o] = bq[o]; ka[o] = bk[o]; }
    for (int c = 0; c < C_; ++c) va[c] = bv[c];

    const float* xb = x + ((size_t)b * C_) * L_ + l;
    for (int c = 0; c < C_; ++c) {
        float xc = xb[(size_t)c * L_];                 // coalesced across lanes
        #pragma unroll
        for (int o = 0; o < CK_; ++o) {
            qa[o] = fmaf(LWq[o * C_ + c], xc, qa[o]);
            ka[o] = fmaf(LWk[o * C_ + c], xc, ka[o]);
        }
        const float4* wr = (const float4*)(LWvT + c * C_);
        #pragma unroll
        for (int j = 0; j < 16; ++j) {
            float4 w = wr[j];
            va[4*j+0] = fmaf(w.x, xc, va[4*j+0]);
            va[4*j+1] = fmaf(w.y, xc, va[4*j+1]);
            va[4*j+2] = fmaf(w.z, xc, va[4*j+2]);
            va[4*j+3] = fmaf(w.w, xc, va[4*j+3]);
        }
    }
    // q: [b][l][o] contiguous in o
    float* qd = qo + ((size_t)b * L_ + l) * CK_;
    ((float4*)qd)[0] = make_float4(qa[0], qa[1], qa[2], qa[3]);
    ((float4*)qd)[1] = make_float4(qa[4], qa[5], qa[6], qa[7]);
    // k: [b][o][l] coalesced in l
    #pragma unroll
    for (int o = 0; o < CK_; ++o)
        ko[((size_t)b * CK_ + o) * L_ + l] = ka[o];
    // vT: [b][l][c] contiguous in c
    float* vd = vTo + ((size_t)b * L_ + l) * C_;
    #pragma unroll
    for (int j = 0; j < 16; ++j)
        ((float4*)vd)[j] = make_float4(va[4*j], va[4*j+1], va[4*j+2], va[4*j+3]);
}

// ---------------- Kernel 2: flash-style column-softmax attention ----------------
// grid: B * (L/MT) blocks of 256 threads. Softmax is over l (rows) per column m.
__global__ __launch_bounds__(256) void attn_kernel(
    const float* __restrict__ qo, const float* __restrict__ ko,
    const float* __restrict__ vTo, const float* __restrict__ x,
    const float* __restrict__ gamma_p, float* __restrict__ out)
{
    __shared__ float Lq[LT_ * CK_];   // q tile [l][o]
    __shared__ float Vt[LT_ * C_];    // v tile [l][c]
    __shared__ float P [LT_ * MT_];   // prob tile [l][m]
    __shared__ float redM[4][MT_];
    __shared__ float redS[4][MT_];
    __shared__ float colM[MT_];
    __shared__ float colS[MT_];       // holds 1/sum

    const int tid = threadIdx.x;
    const int m   = tid & 63;         // mapping A (scores): lane = column
    const int wid = tid >> 6;         // wave id splits l
    const int b   = blockIdx.x >> 6;
    const int m0  = (blockIdx.x & 63) << 6;

    float kreg[CK_];
    #pragma unroll
    for (int o = 0; o < CK_; ++o)
        kreg[o] = ko[((size_t)b * CK_ + o) * L_ + m0 + m];

    const float* qb = qo  + (size_t)b * L_ * CK_;
    const float* vb = vTo + (size_t)b * L_ * C_;

    // ---- pass 1: per-column online (max, sum of exp) over all l ----
    float rmax = -INFINITY, rsum = 0.0f;
    for (int lt = 0; lt < L_ / LT_; ++lt) {
        __syncthreads();
        ((float2*)Lq)[tid] = ((const float2*)(qb + lt * LT_ * CK_))[tid];
        __syncthreads();
        #pragma unroll
        for (int i = 0; i < 16; ++i) {
            const float* qr = Lq + (wid * 16 + i) * CK_;   // broadcast reads
            float s = qr[0] * kreg[0];
            #pragma unroll
            for (int o = 1; o < CK_; ++o) s = fmaf(qr[o], kreg[o], s);
            float nm = fmaxf(rmax, s);
            rsum = fmaf(rsum, __expf(rmax - nm), __expf(s - nm));
            rmax = nm;
        }
    }
    redM[wid][m] = rmax; redS[wid][m] = rsum;
    __syncthreads();
    if (wid == 0) {
        float gm = redM[0][m];
        #pragma unroll
        for (int w = 1; w < 4; ++w) gm = fmaxf(gm, redM[w][m]);
        float gs = 0.0f;
        #pragma unroll
        for (int w = 0; w < 4; ++w) gs += redS[w][m] * __expf(redM[w][m] - gm);
        colM[m] = gm;
        colS[m] = 1.0f / gs;
    }
    __syncthreads();
    const float cmax = colM[m];
    const float rinv = colS[m];

    // ---- pass 2: recompute scores, P = exp(s-max)/sum, accumulate P*V ----
    const int cq = tid >> 4;          // mapping B (PV): 4 channels c = cq*4..+3
    const int mq = tid & 15;          //               4 columns  m = mq*4..+3
    float acc[4][4];
    #pragma unroll
    for (int ci = 0; ci < 4; ++ci)
        #pragma unroll
        for (int mi = 0; mi < 4; ++mi) acc[ci][mi] = 0.0f;

    for (int lt = 0; lt < L_ / LT_; ++lt) {
        __syncthreads();
        ((float2*)Lq)[tid] = ((const float2*)(qb + lt * LT_ * CK_))[tid];
        const float4* vsrc = (const float4*)(vb + lt * LT_ * C_);
        #pragma unroll
        for (int j = 0; j < 4; ++j)
            ((float4*)Vt)[tid + j * 256] = vsrc[tid + j * 256];
        __syncthreads();
        #pragma unroll
        for (int i = 0; i < 16; ++i) {
            int l = wid * 16 + i;
            const float* qr = Lq + l * CK_;
            float s = qr[0] * kreg[0];
            #pragma unroll
            for (int o = 1; o < CK_; ++o) s = fmaf(qr[o], kreg[o], s);
            P[l * MT_ + m] = __expf(s - cmax) * rinv;
        }
        __syncthreads();
        for (int l = 0; l < LT_; ++l) {
            float4 v4 = ((const float4*)(Vt + l * C_ ))[cq];
            float4 p4 = ((const float4*)(P  + l * MT_))[mq];
            acc[0][0] = fmaf(v4.x, p4.x, acc[0][0]);
            acc[0][1] = fmaf(v4.x, p4.y, acc[0][1]);
            acc[0][2] = fmaf(v4.x, p4.z, acc[0][2]);
            acc[0][3] = fmaf(v4.x, p4.w, acc[0][3]);
            acc[1][0] = fmaf(v4.y, p4.x, acc[1][0]);
            acc[1][1] = fmaf(v4.y, p4.y, acc[1][1]);
            acc[1][2] = fmaf(v4.y, p4.z, acc[1][2]);
            acc[1][3] = fmaf(v4.y, p4.w, acc[1][3]);
            acc[2][0] = fmaf(v4.z, p4.x, acc[2][0]);
            acc[2][1] = fmaf(v4.z, p4.y, acc[2][1]);
            acc[2][2] = fmaf(v4.z, p4.z, acc[2][2]);
            acc[2][3] = fmaf(v4.z, p4.w, acc[2][3]);
            acc[3][0] = fmaf(v4.w, p4.x, acc[3][0]);
            acc[3][1] = fmaf(v4.w, p4.y, acc[3][1]);
            acc[3][2] = fmaf(v4.w, p4.z, acc[3][2]);
            acc[3][3] = fmaf(v4.w, p4.w, acc[3][3]);
        }
    }

    // ---- epilogue: out = gamma * attn_out + x ----
    const float g = gamma_p[0];
    #pragma unroll
    for (int ci = 0; ci < 4; ++ci) {
        size_t row = ((size_t)b * C_ + cq * 4 + ci) * L_ + m0 + mq * 4;
        float4 x4 = *(const float4*)(x + row);
        float4 o4;
        o4.x = fmaf(g, acc[ci][0], x4.x);
        o4.y = fmaf(g, acc[ci][1], x4.y);
        o4.z = fmaf(g, acc[ci][2], x4.z);
        o4.w = fmaf(g, acc[ci][3], x4.w);
        *(float4*)(out + row) = o4;
    }
}

extern "C" void kernel_launch(void* const* d_in, const int* in_sizes, int n_in,
                              void* d_out, int out_size, void* d_ws, size_t ws_size,
                              hipStream_t stream) {
    const float* x  = (const float*)d_in[0];
    const float* Wq = (const float*)d_in[1];
    const float* bq = (const float*)d_in[2];
    const float* Wk = (const float*)d_in[3];
    const float* bk = (const float*)d_in[4];
    const float* Wv = (const float*)d_in[5];
    const float* bv = (const float*)d_in[6];
    const float* gm = (const float*)d_in[7];
    float* out = (float*)d_out;

    float* ws  = (float*)d_ws;
    float* qo  = ws;                       // B*L*CK = 262144 floats
    float* ko  = ws + 262144;              // B*CK*L = 262144 floats
    float* vTo = ws + 524288;              // B*L*C  = 2097152 floats

    qkv_kernel<<<dim3(B_ * (L_ / 256)), dim3(256), 0, stream>>>(
        x, Wq, bq, Wk, bk, Wv, bv, qo, ko, vTo);
    attn_kernel<<<dim3(B_ * (L_ / MT_)), dim3(256), 0, stream>>>(
        qo, ko, vTo, x, gm, out);
}

// Round 2
// 200.837 us; speedup vs baseline: 2.3851x; 2.3851x over previous
//
#include <hip/hip_runtime.h>
#include <math.h>

#define B_   8
#define C_   64
#define CK_  8
#define L_   4096
#define MT_  64      // m columns per block (attn)
#define PSTR 72      // P LDS stride in bf16 elems: 144B rows -> 16B aligned, ~2-way banks

typedef __attribute__((ext_vector_type(8))) __bf16 bf16x8;
typedef __attribute__((ext_vector_type(4))) __bf16 bf16x4;
typedef __attribute__((ext_vector_type(4))) float  f32x4;

// ---------------- Kernel 1: QKV projection -> bf16, MFMA-friendly layouts ----
// x: [B,C,L] fp32 -> q: [B,L,8] bf16 ; kT: [B,L,8] bf16 ; V: [B,C,L] bf16
__global__ __launch_bounds__(128) void qkv_kernel(
    const float* __restrict__ x,
    const float* __restrict__ Wq, const float* __restrict__ bq,
    const float* __restrict__ Wk, const float* __restrict__ bk,
    const float* __restrict__ Wv, const float* __restrict__ bv,
    __bf16* __restrict__ qo, __bf16* __restrict__ ko, __bf16* __restrict__ vo)
{
    __shared__ float LWq[CK_ * C_];
    __shared__ float LWk[CK_ * C_];
    __shared__ float LWvT[C_ * C_];   // [c_in][c_out]
    const int tid = threadIdx.x;

    ((float4*)LWq)[tid & 127] = ((const float4*)Wq)[tid];   // 512 floats / 128 thr
    ((float4*)LWk)[tid] = ((const float4*)Wk)[tid];
    #pragma unroll
    for (int j = 0; j < 32; ++j) {
        int f = tid + j * 128;                               // f = c_out*64 + c_in
        LWvT[(f & 63) * C_ + (f >> 6)] = Wv[f];
    }
    __syncthreads();

    const int b = blockIdx.x >> 5;                           // 32 blocks per batch
    const int l = ((blockIdx.x & 31) << 7) + tid;

    float qa[CK_], ka[CK_], va[C_];
    #pragma unroll
    for (int o = 0; o < CK_; ++o) { qa[o] = bq[o]; ka[o] = bk[o]; }
    for (int c = 0; c < C_; ++c) va[c] = bv[c];

    const float* xb = x + ((size_t)b * C_) * L_ + l;
    for (int c = 0; c < C_; ++c) {
        float xc = xb[(size_t)c * L_];
        #pragma unroll
        for (int o = 0; o < CK_; ++o) {
            qa[o] = fmaf(LWq[o * C_ + c], xc, qa[o]);
            ka[o] = fmaf(LWk[o * C_ + c], xc, ka[o]);
        }
        const float4* wr = (const float4*)(LWvT + c * C_);
        #pragma unroll
        for (int j = 0; j < 16; ++j) {
            float4 w = wr[j];
            va[4*j+0] = fmaf(w.x, xc, va[4*j+0]);
            va[4*j+1] = fmaf(w.y, xc, va[4*j+1]);
            va[4*j+2] = fmaf(w.z, xc, va[4*j+2]);
            va[4*j+3] = fmaf(w.w, xc, va[4*j+3]);
        }
    }
    bf16x8 qv, kv;
    #pragma unroll
    for (int o = 0; o < CK_; ++o) { qv[o] = (__bf16)qa[o]; kv[o] = (__bf16)ka[o]; }
    *(bf16x8*)(qo + ((size_t)b * L_ + l) * CK_) = qv;
    *(bf16x8*)(ko + ((size_t)b * L_ + l) * CK_) = kv;
    #pragma unroll
    for (int c = 0; c < C_; ++c)
        vo[((size_t)b * C_ + c) * L_ + l] = (__bf16)va[c];
}

// ---------------- Kernel 2: single-sweep unnormalized-softmax attention -----
// Softmax over l per column m; normalization deferred to epilogue.
// grid: B * (L/64) blocks of 256 threads (4 waves).
__global__ __launch_bounds__(256) void attn_kernel(
    const __bf16* __restrict__ q, const __bf16* __restrict__ kT,
    const __bf16* __restrict__ V, const float* __restrict__ x,
    const float* __restrict__ gamma_p, float* __restrict__ out)
{
    __shared__ __bf16 P[2][MT_ * PSTR];   // column-major: P[m][l], double-buffered
    __shared__ float  cs[4][MT_];
    __shared__ float  cinv[MT_];

    const int tid  = threadIdx.x;
    const int w    = tid >> 6;
    const int lane = tid & 63;
    const int quad = lane >> 4;
    const int l16  = lane & 15;
    const int b    = blockIdx.x >> 6;
    const int m0   = (blockIdx.x & 63) << 6;

    const __bf16* qb = q  + (size_t)b * L_ * CK_;
    const __bf16* kb = kT + ((size_t)b * L_ + m0) * CK_;
    const __bf16* vb = V  + (size_t)b * C_ * L_;

    // Loop-invariant K B-fragments: B[k=o][col=m], real only for quad 0 (o=0..7)
    bf16x8 kf[4];
    #pragma unroll
    for (int j = 0; j < 4; ++j) {
        bf16x8 t = {};
        if (quad == 0) t = *(const bf16x8*)(kb + (size_t)(j * 16 + l16) * CK_);
        kf[j] = t;
    }

    // PV ownership: wave w -> c-subs {2*(w&1), 2*(w&1)+1}, m-subs {2*(w>>1), 2*(w>>1)+1}
    const int cp = (w & 1) * 2;
    const int mp = (w >> 1) * 2;

    f32x4 acc[2][2] = {};
    float csum[4] = {0.f, 0.f, 0.f, 0.f};

    for (int lt = 0; lt < L_ / 64; ++lt) {
        const int l0 = lt * 64;
        __bf16* Pb = &P[lt & 1][0];

        // V A-fragments (independent of P: issue early)
        bf16x8 vf[2][2];
        #pragma unroll
        for (int ci = 0; ci < 2; ++ci)
            #pragma unroll
            for (int kk = 0; kk < 2; ++kk)
                vf[ci][kk] = *(const bf16x8*)(vb + (size_t)((cp + ci) * 16 + l16) * L_
                                              + l0 + kk * 32 + quad * 8);

        // Q A-fragment: rows l0 + w*16 + l16, k=o (quad 0 only)
        bf16x8 qf = {};
        if (quad == 0) qf = *(const bf16x8*)(qb + (size_t)(l0 + w * 16 + l16) * CK_);

        // Scores + P = exp(S) (unnormalized), col-sum accumulate, write P tile
        #pragma unroll
        for (int j = 0; j < 4; ++j) {
            f32x4 s = __builtin_amdgcn_mfma_f32_16x16x32_bf16(qf, kf[j], (f32x4){0.f,0.f,0.f,0.f}, 0, 0, 0);
            float e0 = __expf(s[0]);
            float e1 = __expf(s[1]);
            float e2 = __expf(s[2]);
            float e3 = __expf(s[3]);
            csum[j] += (e0 + e1) + (e2 + e3);
            bf16x4 pk;
            pk[0] = (__bf16)e0; pk[1] = (__bf16)e1; pk[2] = (__bf16)e2; pk[3] = (__bf16)e3;
            // column-major P[m][l]: m = j*16+l16 ; l = w*16 + quad*4 + reg
            *(bf16x4*)(Pb + (j * 16 + l16) * PSTR + w * 16 + quad * 4) = pk;
        }
        __syncthreads();

        // PV: D[c][m] += V[c][l] * P[l][m]
        #pragma unroll
        for (int mi = 0; mi < 2; ++mi) {
            #pragma unroll
            for (int kk = 0; kk < 2; ++kk) {
                bf16x8 pf = *(const bf16x8*)(Pb + ((mp + mi) * 16 + l16) * PSTR + kk * 32 + quad * 8);
                acc[0][mi] = __builtin_amdgcn_mfma_f32_16x16x32_bf16(vf[0][kk], pf, acc[0][mi], 0, 0, 0);
                acc[1][mi] = __builtin_amdgcn_mfma_f32_16x16x32_bf16(vf[1][kk], pf, acc[1][mi], 0, 0, 0);
            }
        }
    }

    // Column-sum reduction: quads (xor 16, 32) then across waves via LDS
    #pragma unroll
    for (int j = 0; j < 4; ++j) {
        float v = csum[j];
        v += __shfl_xor(v, 16);
        v += __shfl_xor(v, 32);
        if (quad == 0) cs[w][j * 16 + l16] = v;
    }
    __syncthreads();
    if (tid < MT_) {
        float t = cs[0][tid] + cs[1][tid] + cs[2][tid] + cs[3][tid];
        cinv[tid] = 1.0f / t;
    }
    __syncthreads();

    const float g = gamma_p[0];
    #pragma unroll
    for (int mi = 0; mi < 2; ++mi) {
        const int m = (mp + mi) * 16 + l16;
        const float sc = g * cinv[m];
        #pragma unroll
        for (int ci = 0; ci < 2; ++ci) {
            #pragma unroll
            for (int r = 0; r < 4; ++r) {
                const int c = (cp + ci) * 16 + quad * 4 + r;
                const size_t idx = ((size_t)b * C_ + c) * L_ + m0 + m;
                out[idx] = fmaf(sc, acc[ci][mi][r], x[idx]);
            }
        }
    }
}

extern "C" void kernel_launch(void* const* d_in, const int* in_sizes, int n_in,
                              void* d_out, int out_size, void* d_ws, size_t ws_size,
                              hipStream_t stream) {
    const float* x  = (const float*)d_in[0];
    const float* Wq = (const float*)d_in[1];
    const float* bq = (const float*)d_in[2];
    const float* Wk = (const float*)d_in[3];
    const float* bk = (const float*)d_in[4];
    const float* Wv = (const float*)d_in[5];
    const float* bv = (const float*)d_in[6];
    const float* gm = (const float*)d_in[7];
    float* out = (float*)d_out;

    __bf16* ws = (__bf16*)d_ws;
    __bf16* qo = ws;                        // B*L*8  = 262144 bf16
    __bf16* ko = ws + 262144;               // B*L*8  = 262144 bf16
    __bf16* vo = ws + 524288;               // B*C*L  = 2097152 bf16

    qkv_kernel<<<dim3(256), dim3(128), 0, stream>>>(x, Wq, bq, Wk, bk, Wv, bv, qo, ko, vo);
    attn_kernel<<<dim3(B_ * (L_ / MT_)), dim3(256), 0, stream>>>(qo, ko, vo, x, gm, out);
}

// Round 3
// 157.034 us; speedup vs baseline: 3.0503x; 1.2789x over previous
//
#include <hip/hip_runtime.h>
#include <math.h>

#define B_   8
#define C_   64
#define CK_  8
#define L_   4096
#define MT_  64      // m columns per attn block
#define PSTR 72      // P LDS stride in bf16 elems
#define NSPL 4       // l-split factor

typedef __attribute__((ext_vector_type(8))) __bf16 bf16x8;
typedef __attribute__((ext_vector_type(4))) __bf16 bf16x4;
typedef __attribute__((ext_vector_type(4))) float  f32x4;

// ---------------- Kernel 1: QKV projection -> bf16 ----------------
// x: [B,C,L] fp32 -> q: [B,L,8] ; kT: [B,L,8] ; vo: [B,C,L]
// 512 blocks x 256 thr; block = (b, 64-l tile). thread: lg = tid&15 (4 l's),
// g = tid>>4: v-channels 4g..4g+3, plus q_g (g<8) or k_{g-8} (g>=8).
__global__ __launch_bounds__(256) void qkv_kernel(
    const float* __restrict__ x,
    const float* __restrict__ Wq, const float* __restrict__ bq,
    const float* __restrict__ Wk, const float* __restrict__ bk,
    const float* __restrict__ Wv, const float* __restrict__ bv,
    __bf16* __restrict__ qo, __bf16* __restrict__ ko, __bf16* __restrict__ vo)
{
    __shared__ float LWq[CK_ * C_];
    __shared__ float LWk[CK_ * C_];
    __shared__ float LWv[C_ * C_];      // row-major [c_out][c_in]
    __shared__ __bf16 Lqs[64 * 8];
    __shared__ __bf16 Lks[64 * 8];

    const int tid = threadIdx.x;
    if (tid < 128) {
        ((float4*)LWq)[tid] = ((const float4*)Wq)[tid];
        ((float4*)LWk)[tid] = ((const float4*)Wk)[tid];
    }
    #pragma unroll
    for (int j = 0; j < 4; ++j)
        ((float4*)LWv)[tid + j * 256] = ((const float4*)Wv)[tid + j * 256];
    __syncthreads();

    const int b  = blockIdx.x >> 6;
    const int l0 = (blockIdx.x & 63) << 6;
    const int lg = tid & 15;
    const int g  = tid >> 4;

    float va[4][4];
    float qk[4];
    #pragma unroll
    for (int j = 0; j < 4; ++j) {
        float bb = bv[4 * g + j];
        va[j][0] = bb; va[j][1] = bb; va[j][2] = bb; va[j][3] = bb;
    }
    {
        float bb = (g < 8) ? bq[g] : bk[g - 8];
        qk[0] = bb; qk[1] = bb; qk[2] = bb; qk[3] = bb;
    }
    const float* wqk = (g < 8) ? (LWq + g * C_) : (LWk + (g - 8) * C_);

    const float* xp = x + ((size_t)b * C_) * L_ + l0 + lg * 4;
    #pragma unroll 4
    for (int c4 = 0; c4 < 16; ++c4) {
        float4 xv[4];
        #pragma unroll
        for (int u = 0; u < 4; ++u)
            xv[u] = *(const float4*)(xp + (size_t)(4 * c4 + u) * L_);
        #pragma unroll
        for (int j = 0; j < 4; ++j) {
            float4 wv = ((const float4*)(LWv + (4 * g + j) * C_))[c4];
            float* a = va[j];
            a[0]=fmaf(wv.x,xv[0].x,a[0]); a[1]=fmaf(wv.x,xv[0].y,a[1]); a[2]=fmaf(wv.x,xv[0].z,a[2]); a[3]=fmaf(wv.x,xv[0].w,a[3]);
            a[0]=fmaf(wv.y,xv[1].x,a[0]); a[1]=fmaf(wv.y,xv[1].y,a[1]); a[2]=fmaf(wv.y,xv[1].z,a[2]); a[3]=fmaf(wv.y,xv[1].w,a[3]);
            a[0]=fmaf(wv.z,xv[2].x,a[0]); a[1]=fmaf(wv.z,xv[2].y,a[1]); a[2]=fmaf(wv.z,xv[2].z,a[2]); a[3]=fmaf(wv.z,xv[2].w,a[3]);
            a[0]=fmaf(wv.w,xv[3].x,a[0]); a[1]=fmaf(wv.w,xv[3].y,a[1]); a[2]=fmaf(wv.w,xv[3].z,a[2]); a[3]=fmaf(wv.w,xv[3].w,a[3]);
        }
        {
            float4 wv = ((const float4*)wqk)[c4];
            qk[0]=fmaf(wv.x,xv[0].x,qk[0]); qk[1]=fmaf(wv.x,xv[0].y,qk[1]); qk[2]=fmaf(wv.x,xv[0].z,qk[2]); qk[3]=fmaf(wv.x,xv[0].w,qk[3]);
            qk[0]=fmaf(wv.y,xv[1].x,qk[0]); qk[1]=fmaf(wv.y,xv[1].y,qk[1]); qk[2]=fmaf(wv.y,xv[1].z,qk[2]); qk[3]=fmaf(wv.y,xv[1].w,qk[3]);
            qk[0]=fmaf(wv.z,xv[2].x,qk[0]); qk[1]=fmaf(wv.z,xv[2].y,qk[1]); qk[2]=fmaf(wv.z,xv[2].z,qk[2]); qk[3]=fmaf(wv.z,xv[2].w,qk[3]);
            qk[0]=fmaf(wv.w,xv[3].x,qk[0]); qk[1]=fmaf(wv.w,xv[3].y,qk[1]); qk[2]=fmaf(wv.w,xv[3].z,qk[2]); qk[3]=fmaf(wv.w,xv[3].w,qk[3]);
        }
    }

    // vo stores: bf16x4 (8B), 16 lanes contiguous per channel row
    #pragma unroll
    for (int j = 0; j < 4; ++j) {
        bf16x4 vv;
        vv[0]=(__bf16)va[j][0]; vv[1]=(__bf16)va[j][1]; vv[2]=(__bf16)va[j][2]; vv[3]=(__bf16)va[j][3];
        *(bf16x4*)(vo + ((size_t)b * C_ + 4 * g + j) * L_ + l0 + lg * 4) = vv;
    }
    // q/k: gather through LDS, then b128 stores
    #pragma unroll
    for (int u = 0; u < 4; ++u) {
        if (g < 8) Lqs[(lg * 4 + u) * 8 + g]       = (__bf16)qk[u];
        else       Lks[(lg * 4 + u) * 8 + (g - 8)] = (__bf16)qk[u];
    }
    __syncthreads();
    if (tid < 64) {
        *(bf16x8*)(qo + ((size_t)b * L_ + l0 + tid) * 8) = *(bf16x8*)(Lqs + tid * 8);
        *(bf16x8*)(ko + ((size_t)b * L_ + l0 + tid) * 8) = *(bf16x8*)(Lks + tid * 8);
    }
}

// ---------------- Kernel 2: phase-1 attention (l-split partials) ----------
// grid: B * 64(mb) * 4(lq). Writes unnormalized partial acc (bf16) + colsum.
__global__ __launch_bounds__(256) void attn_kernel(
    const __bf16* __restrict__ q, const __bf16* __restrict__ kT,
    const __bf16* __restrict__ V,
    __bf16* __restrict__ pacc, float* __restrict__ pcs)
{
    __shared__ __bf16 P[2][MT_ * PSTR];   // column-major P[m][l], double-buffered
    __shared__ float  cs[4][MT_];

    const int tid  = threadIdx.x;
    const int w    = tid >> 6;
    const int lane = tid & 63;
    const int quad = lane >> 4;
    const int l16  = lane & 15;
    const int lq   = blockIdx.x & 3;
    const int mb   = (blockIdx.x >> 2) & 63;
    const int b    = blockIdx.x >> 8;
    const int m0   = mb << 6;

    const __bf16* qb = q  + (size_t)b * L_ * CK_;
    const __bf16* kb = kT + ((size_t)b * L_ + m0) * CK_;
    const __bf16* vb = V  + (size_t)b * C_ * L_;

    bf16x8 kf[4];
    #pragma unroll
    for (int j = 0; j < 4; ++j) {
        bf16x8 t = {};
        if (quad == 0) t = *(const bf16x8*)(kb + (size_t)(j * 16 + l16) * CK_);
        kf[j] = t;
    }

    const int cp = (w & 1) * 2;
    const int mp = (w >> 1) * 2;

    f32x4 acc[2][2] = {};
    float csum[4] = {0.f, 0.f, 0.f, 0.f};

    for (int lt = lq * 16; lt < lq * 16 + 16; ++lt) {
        const int l0 = lt * 64;
        __bf16* Pb = &P[lt & 1][0];

        bf16x8 vf[2][2];
        #pragma unroll
        for (int ci = 0; ci < 2; ++ci)
            #pragma unroll
            for (int kk = 0; kk < 2; ++kk)
                vf[ci][kk] = *(const bf16x8*)(vb + (size_t)((cp + ci) * 16 + l16) * L_
                                              + l0 + kk * 32 + quad * 8);

        bf16x8 qf = {};
        if (quad == 0) qf = *(const bf16x8*)(qb + (size_t)(l0 + w * 16 + l16) * CK_);

        #pragma unroll
        for (int j = 0; j < 4; ++j) {
            f32x4 s = __builtin_amdgcn_mfma_f32_16x16x32_bf16(qf, kf[j], (f32x4){0.f,0.f,0.f,0.f}, 0, 0, 0);
            float e0 = __expf(s[0]);
            float e1 = __expf(s[1]);
            float e2 = __expf(s[2]);
            float e3 = __expf(s[3]);
            csum[j] += (e0 + e1) + (e2 + e3);
            bf16x4 pk;
            pk[0] = (__bf16)e0; pk[1] = (__bf16)e1; pk[2] = (__bf16)e2; pk[3] = (__bf16)e3;
            *(bf16x4*)(Pb + (j * 16 + l16) * PSTR + w * 16 + quad * 4) = pk;
        }
        __syncthreads();

        #pragma unroll
        for (int mi = 0; mi < 2; ++mi) {
            #pragma unroll
            for (int kk = 0; kk < 2; ++kk) {
                bf16x8 pf = *(const bf16x8*)(Pb + ((mp + mi) * 16 + l16) * PSTR + kk * 32 + quad * 8);
                acc[0][mi] = __builtin_amdgcn_mfma_f32_16x16x32_bf16(vf[0][kk], pf, acc[0][mi], 0, 0, 0);
                acc[1][mi] = __builtin_amdgcn_mfma_f32_16x16x32_bf16(vf[1][kk], pf, acc[1][mi], 0, 0, 0);
            }
        }
    }

    // partial column-sum: quad reduce then cross-wave via LDS
    #pragma unroll
    for (int j = 0; j < 4; ++j) {
        float v = csum[j];
        v += __shfl_xor(v, 16);
        v += __shfl_xor(v, 32);
        if (quad == 0) cs[w][j * 16 + l16] = v;
    }
    __syncthreads();
    const size_t pbase = (((size_t)b * 64 + mb) * NSPL + lq);
    if (tid < MT_)
        pcs[pbase * 64 + tid] = cs[0][tid] + cs[1][tid] + cs[2][tid] + cs[3][tid];

    // partial acc -> bf16 [c][m]
    __bf16* pa = pacc + pbase * (64 * 64);
    #pragma unroll
    for (int mi = 0; mi < 2; ++mi) {
        const int m = (mp + mi) * 16 + l16;
        #pragma unroll
        for (int ci = 0; ci < 2; ++ci) {
            #pragma unroll
            for (int r = 0; r < 4; ++r) {
                const int c = (cp + ci) * 16 + quad * 4 + r;
                pa[c * 64 + m] = (__bf16)acc[ci][mi][r];
            }
        }
    }
}

// ---------------- Kernel 3: combine partials, normalize, residual ---------
__global__ __launch_bounds__(256) void combine_kernel(
    const __bf16* __restrict__ pacc, const float* __restrict__ pcs,
    const float* __restrict__ x, const float* __restrict__ gamma_p,
    float* __restrict__ out)
{
    const int tid = threadIdx.x;
    const int m  = tid & 63;
    const int cq = tid >> 6;
    const int b  = blockIdx.x >> 6;
    const int mb = blockIdx.x & 63;

    const size_t base = ((size_t)b * 64 + mb) * NSPL;
    float csv = 0.0f;
    #pragma unroll
    for (int p = 0; p < NSPL; ++p) csv += pcs[(base + p) * 64 + m];
    const float rinv = gamma_p[0] / csv;

    const __bf16* pa = pacc + base * (64 * 64);
    #pragma unroll
    for (int ci = 0; ci < 16; ++ci) {
        const int c = cq * 16 + ci;
        float s = 0.0f;
        #pragma unroll
        for (int p = 0; p < NSPL; ++p)
            s += (float)pa[((size_t)p * 64 + c) * 64 + m];
        const size_t idx = ((size_t)b * C_ + c) * L_ + mb * 64 + m;
        out[idx] = fmaf(rinv, s, x[idx]);
    }
}

extern "C" void kernel_launch(void* const* d_in, const int* in_sizes, int n_in,
                              void* d_out, int out_size, void* d_ws, size_t ws_size,
                              hipStream_t stream) {
    const float* x  = (const float*)d_in[0];
    const float* Wq = (const float*)d_in[1];
    const float* bq = (const float*)d_in[2];
    const float* Wk = (const float*)d_in[3];
    const float* bk = (const float*)d_in[4];
    const float* Wv = (const float*)d_in[5];
    const float* bv = (const float*)d_in[6];
    const float* gm = (const float*)d_in[7];
    float* out = (float*)d_out;

    __bf16* ws   = (__bf16*)d_ws;
    __bf16* qo   = ws;                         // 262144 bf16
    __bf16* ko   = ws + 262144;                // 262144 bf16
    __bf16* vo   = ws + 524288;                // 2097152 bf16
    __bf16* pacc = ws + 2621440;               // 8*64*4*4096 = 8388608 bf16
    float*  pcs  = (float*)(ws + 11010048);    // 8*64*4*64 = 131072 f32

    qkv_kernel<<<dim3(B_ * (L_ / 64)), dim3(256), 0, stream>>>(
        x, Wq, bq, Wk, bk, Wv, bv, qo, ko, vo);
    attn_kernel<<<dim3(B_ * 64 * NSPL), dim3(256), 0, stream>>>(
        qo, ko, vo, pacc, pcs);
    combine_kernel<<<dim3(B_ * 64), dim3(256), 0, stream>>>(
        pacc, pcs, x, gm, out);
}